// Round 4
// baseline (255.481 us; speedup 1.0000x reference)
//
#include <hip/hip_runtime.h>

#define N_NODES 50000
#define N_EDGES 800000
#define IN_CH 256
#define HID 128
#define LAT 64
#define CAP 64       // bucket slots/node; max in-degree ~45 for random 800k/50k
#define NBIN 196     // ceil(50000/256) bins of 256 nodes
#define BINCAP 4864  // Poisson(4082)+12sigma

typedef __attribute__((ext_vector_type(8))) short short8;
typedef __attribute__((ext_vector_type(16))) float f32x16;

static __device__ __forceinline__ unsigned short bf16_rne(float x) {
    unsigned u = __float_as_uint(x);
    unsigned r = (u + 0x7FFFu + ((u >> 16) & 1u)) >> 16;
    return (unsigned short)r;
}
static __device__ __forceinline__ float bf16_to_f(unsigned short h) {
    return __uint_as_float(((unsigned)h) << 16);
}

static __device__ __forceinline__ void add8(uint4 p, float* a) {
    a[0] += __uint_as_float(p.x << 16);
    a[1] += __uint_as_float(p.x & 0xFFFF0000u);
    a[2] += __uint_as_float(p.y << 16);
    a[3] += __uint_as_float(p.y & 0xFFFF0000u);
    a[4] += __uint_as_float(p.z << 16);
    a[5] += __uint_as_float(p.z & 0xFFFF0000u);
    a[6] += __uint_as_float(p.w << 16);
    a[7] += __uint_as_float(p.w & 0xFFFF0000u);
}
static __device__ __forceinline__ void fma8(uint4 p, float m, float* a) {
    a[0] = fmaf(m, __uint_as_float(p.x << 16), a[0]);
    a[1] = fmaf(m, __uint_as_float(p.x & 0xFFFF0000u), a[1]);
    a[2] = fmaf(m, __uint_as_float(p.y << 16), a[2]);
    a[3] = fmaf(m, __uint_as_float(p.y & 0xFFFF0000u), a[3]);
    a[4] = fmaf(m, __uint_as_float(p.z << 16), a[4]);
    a[5] = fmaf(m, __uint_as_float(p.z & 0xFFFF0000u), a[5]);
    a[6] = fmaf(m, __uint_as_float(p.w << 16), a[6]);
    a[7] = fmaf(m, __uint_as_float(p.w & 0xFFFF0000u), a[7]);
}

// ---------------- prep: zero binCnt + split W1/W2 into bf16 hi/lo planes (fragment order) --
template <int K, int NN>
static __device__ __forceinline__ void split_store(const float* __restrict__ W,
                                                   unsigned short* __restrict__ Wf, int i) {
    constexpr int CT = NN / 32;
    int k = i / NN, n = i % NN;
    float w = W[i];
    unsigned short hi = bf16_rne(w);
    unsigned short lo = bf16_rne(w - bf16_to_f(hi));
    size_t off = ((size_t)((k >> 4) * CT + (n >> 5)) * 64 + ((n & 31) + 32 * ((k >> 3) & 1))) * 8 + (k & 7);
    Wf[off] = hi;
    Wf[(size_t)K * NN + off] = lo;
}

__global__ __launch_bounds__(256) void prep_kernel(const float* __restrict__ W1,
                                                   const float* __restrict__ W2,
                                                   int* __restrict__ binCnt,
                                                   unsigned short* __restrict__ W1f,
                                                   unsigned short* __restrict__ W2f) {
    int i = blockIdx.x * blockDim.x + threadIdx.x;
    if (i < NBIN) binCnt[i] = 0;
    if (i < IN_CH * HID) split_store<IN_CH, HID>(W1, W1f, i);
    if (i < HID * LAT) split_store<HID, LAT>(W2, W2f, i);
}

// ---------------- fill pass 1: bin edges by dst>>8 into fixed-cap regions ----------------
// Window-local scatter in pass 2 is the whole point: random 2B stores over the full 6.4MB
// colb (single-pass variant) caused ~7x HBM write amplification (44MB written) and 46us.
__global__ __launch_bounds__(256) void fill1_kernel(const int* __restrict__ ei,
                                                    int* __restrict__ binCnt,
                                                    unsigned int* __restrict__ binBuf, int E) {
    __shared__ int hist[NBIN];
    __shared__ int base[NBIN];
    const int tid = threadIdx.x;
    for (int i = tid; i < NBIN; i += 256) hist[i] = 0;
    __syncthreads();

    const int e0 = blockIdx.x * 2048 + tid;
    unsigned int pk[8];
    int bn[8], ofs[8];
#pragma unroll
    for (int i = 0; i < 8; ++i) {
        int e = e0 + 256 * i;
        bool v = e < E;
        int s = v ? ei[e] : 0;
        int d = v ? ei[E + e] : 0;
        bn[i] = d >> 8;
        pk[i] = (unsigned int)s | ((unsigned int)(d & 255) << 16);
        ofs[i] = v ? atomicAdd(&hist[bn[i]], 1) : -1;
    }
    __syncthreads();
    for (int i = tid; i < NBIN; i += 256)
        base[i] = hist[i] ? atomicAdd(&binCnt[i], hist[i]) : 0;
    __syncthreads();
#pragma unroll
    for (int i = 0; i < 8; ++i) {
        if (ofs[i] >= 0) {
            int p = base[bn[i]] + ofs[i];
            if (p < BINCAP) binBuf[(size_t)bn[i] * BINCAP + p] = pk[i];
        }
    }
}

// ---------------- fill pass 2: one block per bin builds colb + cnt (single-writer) --------
__global__ __launch_bounds__(256) void fill2_kernel(const int* __restrict__ binCnt,
                                                    const unsigned int* __restrict__ binBuf,
                                                    int* __restrict__ cnt,
                                                    unsigned short* __restrict__ colb) {
    __shared__ int lcnt[256];
    const int b = blockIdx.x;
    const int tid = threadIdx.x;
    lcnt[tid] = 0;
    __syncthreads();
    int n = binCnt[b]; if (n > BINCAP) n = BINCAP;
    const int node0 = b << 8;
    const unsigned int* bb = binBuf + (size_t)b * BINCAP;
    int n4 = n & ~3;
    for (int i = tid * 4; i < n4; i += 1024) {
        uint4 pk4 = *(const uint4*)(bb + i);
        unsigned int pks[4] = {pk4.x, pk4.y, pk4.z, pk4.w};
#pragma unroll
        for (int q = 0; q < 4; ++q) {
            unsigned int pk = pks[q];
            int local = pk >> 16;
            int s = pk & 0xFFFF;
            int slot = atomicAdd(&lcnt[local], 1);
            if (slot < CAP) colb[(size_t)(node0 + local) * CAP + slot] = (unsigned short)s;
        }
    }
    for (int i = n4 + tid; i < n; i += 256) {
        unsigned int pk = bb[i];
        int local = pk >> 16;
        int s = pk & 0xFFFF;
        int slot = atomicAdd(&lcnt[local], 1);
        if (slot < CAP) colb[(size_t)(node0 + local) * CAP + slot] = (unsigned short)s;
    }
    __syncthreads();
    int node = node0 + tid;
    if (node < N_NODES) cnt[node] = lcnt[tid];
}

// ---------------- bf16 MFMA GEMM: Cplanes = bf16(rsqrt(deg+1)[m] * (A@W)[m,:]) ------------
// Output in 32-channel PLANE layout: C[(p*M + row)*32 + col32], p = col/32 — sized so each
// plane (M*64B = 3.2MB) fits a 4MB XCD L2 for the downstream chunked aggregation.
// A: AFP32 ? standard fp32 [M][K] (x) : bf16 plane layout [K/32][M][32] (act1).
// B hi+lo planes pre-swizzled in global, staged with plain float4 loads.
template <int K, int NN, bool AFP32>
__global__ __launch_bounds__(256) void gemm_kernel(const void* __restrict__ Av,
                                                   const unsigned short* __restrict__ Wf,
                                                   const int* __restrict__ cnt,
                                                   unsigned short* __restrict__ C, int M) {
    constexpr int CT = NN / 32;                 // col tiles (4 / 2)
    constexpr int NT = (NN == 128) ? 2 : 1;     // col tiles per wave
    __shared__ unsigned short As[4 * 512];           // 2 sl x 2 rowtiles x 1KB = 4KB
    __shared__ unsigned short Bs[2 * 2 * CT * 512];  // planes x sl x CT x 1KB (16/8 KB)

    const int tid = threadIdx.x;
    const int lane = tid & 63;
    const int w = tid >> 6;
    const int row0 = blockIdx.x * 64;
    const int rt = w >> 1;                        // rowtile (32 rows)
    const int ct0 = (NN == 128) ? ((w & 1) * 2) : (w & 1);

    f32x16 acc[NT];
#pragma unroll
    for (int nt = 0; nt < NT; ++nt)
#pragma unroll
        for (int q = 0; q < 16; ++q) acc[nt][q] = 0.0f;

    for (int kt = 0; kt < K; kt += 32) {
        // ---- stage A: 64 rows x 32 k, single bf16 plane, 16B stores ----
        {
            int m = tid >> 2, kc = tid & 3;       // row, 8-k chunk
            int row = row0 + m; if (row >= M) row = M - 1;
            int s = kc >> 1, half = kc & 1, t = m >> 5;
            int ln = (m & 31) + 32 * half;
            uint4 v;
            if constexpr (AFP32) {
                const float* A = (const float*)Av;
                const float4 v0 = *(const float4*)(A + (size_t)row * K + kt + kc * 8);
                const float4 v1 = *(const float4*)(A + (size_t)row * K + kt + kc * 8 + 4);
                v.x = (unsigned)bf16_rne(v0.x) | ((unsigned)bf16_rne(v0.y) << 16);
                v.y = (unsigned)bf16_rne(v0.z) | ((unsigned)bf16_rne(v0.w) << 16);
                v.z = (unsigned)bf16_rne(v1.x) | ((unsigned)bf16_rne(v1.y) << 16);
                v.w = (unsigned)bf16_rne(v1.z) | ((unsigned)bf16_rne(v1.w) << 16);
            } else {
                // A in plane layout: K-tile (kt..kt+32) == plane kt>>5; kc*8 within plane.
                const unsigned short* A = (const unsigned short*)Av;
                v = *(const uint4*)(A + ((size_t)(kt >> 5) * M + row) * 32 + kc * 8);
            }
            *(uint4*)&As[((s * 2 + t) << 9) + (ln << 3)] = v;
        }
        // ---- stage B: plain vector copy (pre-swizzled in global) ----
        {
            const int sg0 = kt >> 4;
#pragma unroll
            for (int i0 = 0; i0 < CT * 256; i0 += 256) {
                int i = i0 + tid;
                int psl = i / (CT * 64), rem = i % (CT * 64);
                int p = psl >> 1, sl = psl & 1;
                const uint4* src = (const uint4*)(Wf + (size_t)p * K * NN + (size_t)(sg0 + sl) * CT * 512);
                ((uint4*)Bs)[i] = src[rem];
            }
        }
        __syncthreads();

#pragma unroll
        for (int sl = 0; sl < 2; ++sl) {
            short8 a = *(const short8*)&As[((sl * 2 + rt) << 9) + (lane << 3)];
            short8 bh[NT], bl[NT];
#pragma unroll
            for (int nt = 0; nt < NT; ++nt) {
                bh[nt] = *(const short8*)&Bs[((sl * CT + ct0 + nt) << 9) + (lane << 3)];
                bl[nt] = *(const short8*)&Bs[(((2 + sl) * CT + ct0 + nt) << 9) + (lane << 3)];
            }
#pragma unroll
            for (int nt = 0; nt < NT; ++nt) {
                acc[nt] = __builtin_amdgcn_mfma_f32_32x32x16_bf16(a, bh[nt], acc[nt], 0, 0, 0);
                acc[nt] = __builtin_amdgcn_mfma_f32_32x32x16_bf16(a, bl[nt], acc[nt], 0, 0, 0);
            }
        }
        __syncthreads();
    }

    // epilogue: scale by rsqrt(deg+1), convert bf16, store into plane layout
#pragma unroll
    for (int r = 0; r < 16; ++r) {
        int rowl = rt * 32 + (r & 3) + 8 * (r >> 2) + 4 * (lane >> 5);
        int row = row0 + rowl;
        if (row < M) {
            float sc = rsqrtf((float)cnt[row] + 1.0f);
#pragma unroll
            for (int nt = 0; nt < NT; ++nt) {
                int p = ct0 + nt;
                C[((size_t)p * M + row) * 32 + (lane & 31)] = bf16_rne(acc[nt][r] * sc);
            }
        }
    }
}

// ---------------- chunked bucket aggregation over bf16 feature PLANES ----------------
// out[i] = relu(dis_i*(hs[i]+sum_nbr hs[src]) + b). hs is [C/32][N][32] bf16; each plane
// is 3.2MB (< 4MB XCD L2). Grid is chunk-major (all CUs gather from the SAME plane at a
// time) so gathers are L2-hits instead of L3 random access. One wave per (node, chunk):
// 4 lanes/row x 16 rows in flight, 2 predicated 16-row batches per iter (avg deg 16 -> 1).
// OBF16: bf16 plane output (act1) vs fp32 standard-layout output (d_out).
template <int C, bool OBF16>
__global__ __launch_bounds__(256) void aggc_kernel(const int* __restrict__ cnt,
                                                   const unsigned short* __restrict__ colb,
                                                   const unsigned short* __restrict__ hs,
                                                   const float* __restrict__ bias,
                                                   void* __restrict__ outv, int N) {
    constexpr int NB = (N_NODES + 3) / 4;   // blocks per chunk (4 nodes/block)
    const int chunk = blockIdx.x / NB;
    const int node = (blockIdx.x % NB) * 4 + (threadIdx.x >> 6);
    const int lane = threadIdx.x & 63;
    if (node >= N) return;
    const int g = lane >> 2;   // 0..15: row slot
    const int c = lane & 3;    // 0..3: 8-channel piece of the 32-ch plane row

    const unsigned short* plane = hs + (size_t)chunk * N * 32;

    // independent loads up front
    uint4 selfp = *(const uint4*)(plane + (size_t)node * 32 + c * 8);
    int rawc = (int)colb[(size_t)node * CAP + lane];  // garbage beyond kk, masked below
    int deg = cnt[node];
    int kk = deg < CAP ? deg : CAP;

    float acc[8];
#pragma unroll
    for (int q = 0; q < 8; ++q) acc[q] = 0.0f;
    if (g == 0) add8(selfp, acc);  // self loop

    int myc = (lane < kk) ? rawc : 0;

    for (int j = 0; j < kk; j += 32) {
        bool v0 = (j + g) < kk, v1 = (j + g + 16) < kk;
        int s0 = __shfl(myc, v0 ? (j + g) : 0);
        int s1 = __shfl(myc, v1 ? (j + g + 16) : 0);
        uint4 p0 = *(const uint4*)(plane + (size_t)s0 * 32 + c * 8);
        uint4 p1 = *(const uint4*)(plane + (size_t)s1 * 32 + c * 8);
        fma8(p0, v0 ? 1.0f : 0.0f, acc);
        fma8(p1, v1 ? 1.0f : 0.0f, acc);
    }

#pragma unroll
    for (int s = 4; s < 64; s <<= 1)
#pragma unroll
        for (int q = 0; q < 8; ++q) acc[q] += __shfl_xor(acc[q], s);

    if (lane < 4) {
        float di = rsqrtf((float)deg + 1.0f);
        float o[8];
#pragma unroll
        for (int q = 0; q < 8; ++q)
            o[q] = fmaxf(fmaf(di, acc[q], bias[chunk * 32 + c * 8 + q]), 0.0f);
        if constexpr (OBF16) {
            unsigned short* out = (unsigned short*)outv;
            unsigned short* op = out + ((size_t)chunk * N + node) * 32 + c * 8;
            ushort4 lo4 = make_ushort4(bf16_rne(o[0]), bf16_rne(o[1]), bf16_rne(o[2]), bf16_rne(o[3]));
            ushort4 hi4 = make_ushort4(bf16_rne(o[4]), bf16_rne(o[5]), bf16_rne(o[6]), bf16_rne(o[7]));
            *(ushort4*)op = lo4;
            *(ushort4*)(op + 4) = hi4;
        } else {
            float* out = (float*)outv;
            float* op = out + (size_t)node * C + chunk * 32 + c * 8;
            float4 o0 = {o[0], o[1], o[2], o[3]};
            float4 o1 = {o[4], o[5], o[6], o[7]};
            *(float4*)op = o0;
            *(float4*)(op + 4) = o1;
        }
    }
}

extern "C" void kernel_launch(void* const* d_in, const int* in_sizes, int n_in,
                              void* d_out, int out_size, void* d_ws, size_t ws_size,
                              hipStream_t stream) {
    const float* x  = (const float*)d_in[0];
    const int*   ei = (const int*)d_in[1];
    const float* W1 = (const float*)d_in[2];
    const float* b1 = (const float*)d_in[3];
    const float* W2 = (const float*)d_in[4];
    const float* b2 = (const float*)d_in[5];

    const int N = N_NODES, E = N_EDGES;
    const int NB = (N_NODES + 3) / 4;  // agg blocks per chunk

    char* ws = (char*)d_ws;
    size_t off = 0;
    auto alloc = [&](size_t bytes) {
        void* p = ws + off;
        off = (off + bytes + 255) & ~(size_t)255;
        return p;
    };
    int*            cnt    = (int*)alloc((size_t)N * 4);                   // 200 KB
    unsigned short* colb   = (unsigned short*)alloc((size_t)N * CAP * 2);  // 6.4 MB
    int*            binCnt = (int*)alloc((size_t)NBIN * 4);
    unsigned int*   binBuf = (unsigned int*)alloc((size_t)NBIN * BINCAP * 4);  // 3.8 MB
    unsigned short* W1f    = (unsigned short*)alloc((size_t)2 * IN_CH * HID * 2);  // 128 KB
    unsigned short* W2f    = (unsigned short*)alloc((size_t)2 * HID * LAT * 2);    // 32 KB
    unsigned short* h1s    = (unsigned short*)alloc((size_t)N * HID * 2);  // 12.8 MB, 4 planes
    unsigned short* act1   = (unsigned short*)alloc((size_t)N * HID * 2);  // 12.8 MB, 4 planes
    unsigned short* h2s    = h1s;  // h1s dead after agg1 (needs 6.4 MB = 2 planes, slot has 12.8)

    prep_kernel<<<(N + 255) / 256, 256, 0, stream>>>(W1, W2, binCnt, W1f, W2f);
    fill1_kernel<<<(E + 2047) / 2048, 256, 0, stream>>>(ei, binCnt, binBuf, E);
    fill2_kernel<<<NBIN, 256, 0, stream>>>(binCnt, binBuf, cnt, colb);

    // layer 1: h1s = bf16(dis*(x@W1)) [4 planes]; act1 = bf16(relu(dis*(self+nbrs)+b1)) [4 planes]
    gemm_kernel<IN_CH, HID, true><<<(N + 63) / 64, 256, 0, stream>>>(x, W1f, cnt, h1s, N);
    aggc_kernel<HID, true><<<4 * NB, 256, 0, stream>>>(cnt, colb, h1s, b1, act1, N);

    // layer 2: h2s = bf16(dis*(act1@W2)) [2 planes]; out = relu(dis*(self+nbrs)+b2) [fp32, std]
    gemm_kernel<HID, LAT, false><<<(N + 63) / 64, 256, 0, stream>>>(act1, W2f, cnt, h2s, N);
    aggc_kernel<LAT, false><<<2 * NB, 256, 0, stream>>>(cnt, colb, h2s, b2, d_out, N);
}

// Round 5
// 190.298 us; speedup vs baseline: 1.3425x; 1.3425x over previous
//
#include <hip/hip_runtime.h>

#define N_NODES 50000
#define N_EDGES 800000
#define IN_CH 256
#define HID 128
#define LAT 64
#define CAP 64       // bucket slots/node; max in-degree ~45 for random 800k/50k
#define NBIN 196     // ceil(50000/256) bins of 256 nodes
#define BINCAP 4864  // Poisson(4082)+12sigma

typedef __attribute__((ext_vector_type(8))) short short8;
typedef __attribute__((ext_vector_type(16))) float f32x16;

static __device__ __forceinline__ unsigned short bf16_rne(float x) {
    unsigned u = __float_as_uint(x);
    unsigned r = (u + 0x7FFFu + ((u >> 16) & 1u)) >> 16;
    return (unsigned short)r;
}
static __device__ __forceinline__ float bf16_to_f(unsigned short h) {
    return __uint_as_float(((unsigned)h) << 16);
}

static __device__ __forceinline__ void add8(uint4 p, float* a) {
    a[0] += __uint_as_float(p.x << 16);
    a[1] += __uint_as_float(p.x & 0xFFFF0000u);
    a[2] += __uint_as_float(p.y << 16);
    a[3] += __uint_as_float(p.y & 0xFFFF0000u);
    a[4] += __uint_as_float(p.z << 16);
    a[5] += __uint_as_float(p.z & 0xFFFF0000u);
    a[6] += __uint_as_float(p.w << 16);
    a[7] += __uint_as_float(p.w & 0xFFFF0000u);
}
static __device__ __forceinline__ void fma8(uint4 p, float m, float* a) {
    a[0] = fmaf(m, __uint_as_float(p.x << 16), a[0]);
    a[1] = fmaf(m, __uint_as_float(p.x & 0xFFFF0000u), a[1]);
    a[2] = fmaf(m, __uint_as_float(p.y << 16), a[2]);
    a[3] = fmaf(m, __uint_as_float(p.y & 0xFFFF0000u), a[3]);
    a[4] = fmaf(m, __uint_as_float(p.z << 16), a[4]);
    a[5] = fmaf(m, __uint_as_float(p.z & 0xFFFF0000u), a[5]);
    a[6] = fmaf(m, __uint_as_float(p.w << 16), a[6]);
    a[7] = fmaf(m, __uint_as_float(p.w & 0xFFFF0000u), a[7]);
}

// ---------------- prep: zero binCnt + split W1/W2 into bf16 hi/lo planes (fragment order) --
template <int K, int NN>
static __device__ __forceinline__ void split_store(const float* __restrict__ W,
                                                   unsigned short* __restrict__ Wf, int i) {
    constexpr int CT = NN / 32;
    int k = i / NN, n = i % NN;
    float w = W[i];
    unsigned short hi = bf16_rne(w);
    unsigned short lo = bf16_rne(w - bf16_to_f(hi));
    size_t off = ((size_t)((k >> 4) * CT + (n >> 5)) * 64 + ((n & 31) + 32 * ((k >> 3) & 1))) * 8 + (k & 7);
    Wf[off] = hi;
    Wf[(size_t)K * NN + off] = lo;
}

__global__ __launch_bounds__(256) void prep_kernel(const float* __restrict__ W1,
                                                   const float* __restrict__ W2,
                                                   int* __restrict__ binCnt,
                                                   unsigned short* __restrict__ W1f,
                                                   unsigned short* __restrict__ W2f) {
    int i = blockIdx.x * blockDim.x + threadIdx.x;
    if (i < NBIN) binCnt[i] = 0;
    if (i < IN_CH * HID) split_store<IN_CH, HID>(W1, W1f, i);
    if (i < HID * LAT) split_store<HID, LAT>(W2, W2f, i);
}

// ---------------- fill pass 1: bin edges by dst>>8 into fixed-cap regions ----------------
// Window-local scatter in pass 2 is the whole point: random 2B stores over the full 6.4MB
// colb (single-pass variant) caused ~7x HBM write amplification (44MB written) and 46us.
__global__ __launch_bounds__(256) void fill1_kernel(const int* __restrict__ ei,
                                                    int* __restrict__ binCnt,
                                                    unsigned int* __restrict__ binBuf, int E) {
    __shared__ int hist[NBIN];
    __shared__ int base[NBIN];
    const int tid = threadIdx.x;
    for (int i = tid; i < NBIN; i += 256) hist[i] = 0;
    __syncthreads();

    const int e0 = blockIdx.x * 2048 + tid;
    unsigned int pk[8];
    int bn[8], ofs[8];
#pragma unroll
    for (int i = 0; i < 8; ++i) {
        int e = e0 + 256 * i;
        bool v = e < E;
        int s = v ? ei[e] : 0;
        int d = v ? ei[E + e] : 0;
        bn[i] = d >> 8;
        pk[i] = (unsigned int)s | ((unsigned int)(d & 255) << 16);
        ofs[i] = v ? atomicAdd(&hist[bn[i]], 1) : -1;
    }
    __syncthreads();
    for (int i = tid; i < NBIN; i += 256)
        base[i] = hist[i] ? atomicAdd(&binCnt[i], hist[i]) : 0;
    __syncthreads();
#pragma unroll
    for (int i = 0; i < 8; ++i) {
        if (ofs[i] >= 0) {
            int p = base[bn[i]] + ofs[i];
            if (p < BINCAP) binBuf[(size_t)bn[i] * BINCAP + p] = pk[i];
        }
    }
}

// ---------------- fill pass 2: one block per bin builds colb + cnt (single-writer) --------
__global__ __launch_bounds__(256) void fill2_kernel(const int* __restrict__ binCnt,
                                                    const unsigned int* __restrict__ binBuf,
                                                    int* __restrict__ cnt,
                                                    unsigned short* __restrict__ colb) {
    __shared__ int lcnt[256];
    const int b = blockIdx.x;
    const int tid = threadIdx.x;
    lcnt[tid] = 0;
    __syncthreads();
    int n = binCnt[b]; if (n > BINCAP) n = BINCAP;
    const int node0 = b << 8;
    const unsigned int* bb = binBuf + (size_t)b * BINCAP;
    int n4 = n & ~3;
    for (int i = tid * 4; i < n4; i += 1024) {
        uint4 pk4 = *(const uint4*)(bb + i);
        unsigned int pks[4] = {pk4.x, pk4.y, pk4.z, pk4.w};
#pragma unroll
        for (int q = 0; q < 4; ++q) {
            unsigned int pk = pks[q];
            int local = pk >> 16;
            int s = pk & 0xFFFF;
            int slot = atomicAdd(&lcnt[local], 1);
            if (slot < CAP) colb[(size_t)(node0 + local) * CAP + slot] = (unsigned short)s;
        }
    }
    for (int i = n4 + tid; i < n; i += 256) {
        unsigned int pk = bb[i];
        int local = pk >> 16;
        int s = pk & 0xFFFF;
        int slot = atomicAdd(&lcnt[local], 1);
        if (slot < CAP) colb[(size_t)(node0 + local) * CAP + slot] = (unsigned short)s;
    }
    __syncthreads();
    int node = node0 + tid;
    if (node < N_NODES) cnt[node] = lcnt[tid];
}

// ---------------- bf16 MFMA GEMM: C[m,:] = bf16(rsqrt(deg+1)[m] * (A@W)[m,:]) ------------
// BM=64, BK=32, 4 waves -> 782 blocks (~3/CU for latency hiding through barriers).
// Wave tile: NN=128: 32 rows x 64 cols (rt=w>>1, ct0=(w&1)*2, NT=2);
//            NN=64:  32 rows x 32 cols (rt=w>>1, ct0=w&1,     NT=1).
// A single bf16 plane (AFP32: fp32->bf16 in staging; else pure copy-swizzle), 16B LDS stores.
// B hi+lo planes pre-swizzled in global, staged with plain float4 loads.
template <int K, int NN, bool AFP32>
__global__ __launch_bounds__(256) void gemm_kernel(const void* __restrict__ Av,
                                                   const unsigned short* __restrict__ Wf,
                                                   const int* __restrict__ cnt,
                                                   unsigned short* __restrict__ C, int M) {
    constexpr int CT = NN / 32;                 // col tiles (4 / 2)
    constexpr int NT = (NN == 128) ? 2 : 1;     // col tiles per wave
    __shared__ unsigned short As[4 * 512];           // 2 sl x 2 rowtiles x 1KB = 4KB
    __shared__ unsigned short Bs[2 * 2 * CT * 512];  // planes x sl x CT x 1KB (16/8 KB)

    const int tid = threadIdx.x;
    const int lane = tid & 63;
    const int w = tid >> 6;
    const int row0 = blockIdx.x * 64;
    const int rt = w >> 1;                        // rowtile (32 rows)
    const int ct0 = (NN == 128) ? ((w & 1) * 2) : (w & 1);

    f32x16 acc[NT];
#pragma unroll
    for (int nt = 0; nt < NT; ++nt)
#pragma unroll
        for (int q = 0; q < 16; ++q) acc[nt][q] = 0.0f;

    for (int kt = 0; kt < K; kt += 32) {
        // ---- stage A: 64 rows x 32 k, single bf16 plane, 16B stores ----
        {
            int m = tid >> 2, kc = tid & 3;       // row, 8-k chunk
            int row = row0 + m; if (row >= M) row = M - 1;
            int s = kc >> 1, half = kc & 1, t = m >> 5;
            int ln = (m & 31) + 32 * half;
            uint4 v;
            if constexpr (AFP32) {
                const float* A = (const float*)Av;
                const float4 v0 = *(const float4*)(A + (size_t)row * K + kt + kc * 8);
                const float4 v1 = *(const float4*)(A + (size_t)row * K + kt + kc * 8 + 4);
                v.x = (unsigned)bf16_rne(v0.x) | ((unsigned)bf16_rne(v0.y) << 16);
                v.y = (unsigned)bf16_rne(v0.z) | ((unsigned)bf16_rne(v0.w) << 16);
                v.z = (unsigned)bf16_rne(v1.x) | ((unsigned)bf16_rne(v1.y) << 16);
                v.w = (unsigned)bf16_rne(v1.z) | ((unsigned)bf16_rne(v1.w) << 16);
            } else {
                const unsigned short* A = (const unsigned short*)Av;
                v = *(const uint4*)(A + (size_t)row * K + kt + kc * 8);
            }
            *(uint4*)&As[((s * 2 + t) << 9) + (ln << 3)] = v;
        }
        // ---- stage B: plain vector copy (pre-swizzled in global) ----
        {
            const int sg0 = kt >> 4;
#pragma unroll
            for (int i0 = 0; i0 < CT * 256; i0 += 256) {
                int i = i0 + tid;
                int psl = i / (CT * 64), rem = i % (CT * 64);
                int p = psl >> 1, sl = psl & 1;
                const uint4* src = (const uint4*)(Wf + (size_t)p * K * NN + (size_t)(sg0 + sl) * CT * 512);
                ((uint4*)Bs)[i] = src[rem];
            }
        }
        __syncthreads();

#pragma unroll
        for (int sl = 0; sl < 2; ++sl) {
            short8 a = *(const short8*)&As[((sl * 2 + rt) << 9) + (lane << 3)];
            short8 bh[NT], bl[NT];
#pragma unroll
            for (int nt = 0; nt < NT; ++nt) {
                bh[nt] = *(const short8*)&Bs[((sl * CT + ct0 + nt) << 9) + (lane << 3)];
                bl[nt] = *(const short8*)&Bs[(((2 + sl) * CT + ct0 + nt) << 9) + (lane << 3)];
            }
#pragma unroll
            for (int nt = 0; nt < NT; ++nt) {
                acc[nt] = __builtin_amdgcn_mfma_f32_32x32x16_bf16(a, bh[nt], acc[nt], 0, 0, 0);
                acc[nt] = __builtin_amdgcn_mfma_f32_32x32x16_bf16(a, bl[nt], acc[nt], 0, 0, 0);
            }
        }
        __syncthreads();
    }

    // epilogue: scale by rsqrt(deg+1), convert bf16, store
#pragma unroll
    for (int r = 0; r < 16; ++r) {
        int rowl = rt * 32 + (r & 3) + 8 * (r >> 2) + 4 * (lane >> 5);
        int row = row0 + rowl;
        if (row < M) {
            float sc = rsqrtf((float)cnt[row] + 1.0f);
#pragma unroll
            for (int nt = 0; nt < NT; ++nt) {
                int col = (ct0 + nt) * 32 + (lane & 31);
                C[(size_t)row * NN + col] = bf16_rne(acc[nt][r] * sc);
            }
        }
    }
}

// ---------------- group-per-node aggregation, zero cross-lane ops ----------------
// out[i] = relu(dis_i*(hs[i]+sum_nbr hs[src]) + b); OBF16 selects bf16 vs fp32 output.
// LPN lanes own one node (16 for C=128, 8 for C=64); each lane owns its 8 channels across
// ALL neighbors -> no shuffle-broadcast, no shuffle-reduce. Waves: 12.5k / 6.25k (vs 50k):
// R4 counters showed agg is VALU/wave-overhead bound (VALUBusy 78%, HBM 12%), so the win
// is fewer waves x less per-wave machinery, at identical gather traffic.
// Neighbor indices: one broadcast ushort4 load per 4 neighbors (colb row is L1-hot);
// 4 independent idx->row gather chains per step (ILP=4). Tail predicates the INDEX to 0
// (row 0 is finite) and the multiplier to 0 -- never 0 x poison(NaN).
template <int C, bool OBF16>
__global__ __launch_bounds__(256) void agg_kernel(const int* __restrict__ cnt,
                                                  const unsigned short* __restrict__ colb,
                                                  const unsigned short* __restrict__ hs,
                                                  const float* __restrict__ bias,
                                                  void* __restrict__ outv, int N) {
    constexpr int LPN = C / 8;       // lanes per node: 16 (C=128) / 8 (C=64)
    constexpr int NPB = 256 / LPN;   // nodes per block: 16 / 32
    const int node = blockIdx.x * NPB + (int)(threadIdx.x / LPN);
    const int u = threadIdx.x % LPN; // 8-channel piece owned by this lane
    if (node >= N) return;

    const unsigned short* __restrict__ hbase = hs + u * 8;

    // independent loads up front
    uint4 selfp = *(const uint4*)(hbase + (size_t)node * C);
    int deg = cnt[node];
    const unsigned short* __restrict__ cb = colb + (size_t)node * CAP;
    int kk = deg < CAP ? deg : CAP;

    float acc[8];
#pragma unroll
    for (int q = 0; q < 8; ++q) acc[q] = 0.0f;
    add8(selfp, acc);  // self loop

    int j = 0;
    for (; j + 4 <= kk; j += 4) {
        ushort4 s4 = *(const ushort4*)(cb + j);  // broadcast, 8B-aligned, L1-hot
        uint4 p0 = *(const uint4*)(hbase + (size_t)s4.x * C);
        uint4 p1 = *(const uint4*)(hbase + (size_t)s4.y * C);
        uint4 p2 = *(const uint4*)(hbase + (size_t)s4.z * C);
        uint4 p3 = *(const uint4*)(hbase + (size_t)s4.w * C);
        add8(p0, acc); add8(p1, acc); add8(p2, acc); add8(p3, acc);
    }
    if (j < kk) {                                 // tail: <=3 neighbors, predicated
        ushort4 s4 = *(const ushort4*)(cb + j);   // in-bounds (CAP=64), values masked below
        bool v1 = (j + 1) < kk, v2 = (j + 2) < kk;
        int t0 = s4.x;                            // j<kk guaranteed here
        int t1 = v1 ? (int)s4.y : 0;
        int t2 = v2 ? (int)s4.z : 0;
        uint4 p0 = *(const uint4*)(hbase + (size_t)t0 * C);
        uint4 p1 = *(const uint4*)(hbase + (size_t)t1 * C);
        uint4 p2 = *(const uint4*)(hbase + (size_t)t2 * C);
        add8(p0, acc);
        fma8(p1, v1 ? 1.0f : 0.0f, acc);
        fma8(p2, v2 ? 1.0f : 0.0f, acc);
    }

    float di = rsqrtf((float)deg + 1.0f);
    const float4 b0 = *(const float4*)(bias + u * 8);
    const float4 b1 = *(const float4*)(bias + u * 8 + 4);
    float o[8];
    o[0] = fmaxf(fmaf(di, acc[0], b0.x), 0.0f);
    o[1] = fmaxf(fmaf(di, acc[1], b0.y), 0.0f);
    o[2] = fmaxf(fmaf(di, acc[2], b0.z), 0.0f);
    o[3] = fmaxf(fmaf(di, acc[3], b0.w), 0.0f);
    o[4] = fmaxf(fmaf(di, acc[4], b1.x), 0.0f);
    o[5] = fmaxf(fmaf(di, acc[5], b1.y), 0.0f);
    o[6] = fmaxf(fmaf(di, acc[6], b1.z), 0.0f);
    o[7] = fmaxf(fmaf(di, acc[7], b1.w), 0.0f);

    if constexpr (OBF16) {
        uint4 st;
        st.x = (unsigned)bf16_rne(o[0]) | ((unsigned)bf16_rne(o[1]) << 16);
        st.y = (unsigned)bf16_rne(o[2]) | ((unsigned)bf16_rne(o[3]) << 16);
        st.z = (unsigned)bf16_rne(o[4]) | ((unsigned)bf16_rne(o[5]) << 16);
        st.w = (unsigned)bf16_rne(o[6]) | ((unsigned)bf16_rne(o[7]) << 16);
        *(uint4*)((unsigned short*)outv + (size_t)node * C + u * 8) = st;
    } else {
        float* op = (float*)outv + (size_t)node * C + u * 8;
        float4 o0 = {o[0], o[1], o[2], o[3]};
        float4 o1 = {o[4], o[5], o[6], o[7]};
        *(float4*)op = o0;
        *(float4*)(op + 4) = o1;
    }
}

extern "C" void kernel_launch(void* const* d_in, const int* in_sizes, int n_in,
                              void* d_out, int out_size, void* d_ws, size_t ws_size,
                              hipStream_t stream) {
    const float* x  = (const float*)d_in[0];
    const int*   ei = (const int*)d_in[1];
    const float* W1 = (const float*)d_in[2];
    const float* b1 = (const float*)d_in[3];
    const float* W2 = (const float*)d_in[4];
    const float* b2 = (const float*)d_in[5];

    const int N = N_NODES, E = N_EDGES;

    char* ws = (char*)d_ws;
    size_t off = 0;
    auto alloc = [&](size_t bytes) {
        void* p = ws + off;
        off = (off + bytes + 255) & ~(size_t)255;
        return p;
    };
    int*            cnt    = (int*)alloc((size_t)N * 4);                   // 200 KB
    unsigned short* colb   = (unsigned short*)alloc((size_t)N * CAP * 2);  // 6.4 MB
    int*            binCnt = (int*)alloc((size_t)NBIN * 4);
    unsigned int*   binBuf = (unsigned int*)alloc((size_t)NBIN * BINCAP * 4);  // 3.8 MB
    unsigned short* W1f    = (unsigned short*)alloc((size_t)2 * IN_CH * HID * 2);  // 128 KB
    unsigned short* W2f    = (unsigned short*)alloc((size_t)2 * HID * LAT * 2);    // 32 KB
    unsigned short* h1s    = (unsigned short*)alloc((size_t)N * HID * 2);  // 12.8 MB bf16
    unsigned short* act1   = (unsigned short*)alloc((size_t)N * HID * 2);  // 12.8 MB bf16
    unsigned short* h2s    = h1s;  // h1s dead after agg1 (needs 6.4 MB, slot has 12.8)

    prep_kernel<<<(N + 255) / 256, 256, 0, stream>>>(W1, W2, binCnt, W1f, W2f);
    fill1_kernel<<<(E + 2047) / 2048, 256, 0, stream>>>(ei, binCnt, binBuf, E);
    fill2_kernel<<<NBIN, 256, 0, stream>>>(binCnt, binBuf, cnt, colb);

    // layer 1: h1s = bf16(dis*(x@W1)); act1 = bf16(relu(dis*(self+nbrs) + b1))
    gemm_kernel<IN_CH, HID, true><<<(N + 63) / 64, 256, 0, stream>>>(x, W1f, cnt, h1s, N);
    agg_kernel<HID, true><<<(N + 15) / 16, 256, 0, stream>>>(cnt, colb, h1s, b1, act1, N);

    // layer 2: h2s = bf16(dis*(act1@W2)); out = relu(dis*(self+nbrs) + b2)  [fp32]
    gemm_kernel<HID, LAT, false><<<(N + 63) / 64, 256, 0, stream>>>(act1, W2f, cnt, h2s, N);
    agg_kernel<LAT, false><<<(N + 31) / 32, 256, 0, stream>>>(cnt, colb, h2s, b2, d_out, N);
}